// Round 15
// baseline (281.353 us; speedup 1.0000x reference)
//
#include <hip/hip_runtime.h>
#include <hip/hip_fp16.h>
#include <math.h>

#define N_NODES 50000
#define N_EDGES 800000
#define ETOT    850000   // N_EDGES + N_NODES self-loops
#define GRAPHS  64
#define FIN     128
#define HC      128      // HEADS*HID
#define OUTF    10
#define NEG     0.2f

#define NBUCK   196      // ceil(50000/256) buckets of 256 dst nodes
#define BCAP    8192     // slots per bucket (mean 4338, sigma ~66 -> safe)
#define EPT     8        // edges per thread in bucketA
#define GEMMB   782      // (N_NODES+63)/64
#define ABLK    416      // (ETOT+2047)/2048

using half8   = __attribute__((ext_vector_type(8))) _Float16;
using float4v = __attribute__((ext_vector_type(4))) float;

// Feature-sliced fp16 layout: table[(slice*N_NODES + node)*32 + c], c in [0,32).
// slice s holds global features s*32 .. s*32+31. One slice row = 64 B.

// ---------------- setup: W->fp16 transposed, zero tails + pool sums ----------------
__global__ void setupk(const float* __restrict__ W1, const float* __restrict__ W2,
                       _Float16* __restrict__ WT1, _Float16* __restrict__ WT2,
                       int* __restrict__ tails, float* __restrict__ sums) {
    int i = blockIdx.x * 256 + threadIdx.x;
    if (i < 16384) {
        int n = i >> 7, k = i & 127;          // output index WT[n][k]
        WT1[i] = (_Float16)W1[k * 128 + n];
        WT2[i] = (_Float16)W2[k * 128 + n];
    }
    if (i < NBUCK) tails[i] = 0;
    if (i < GRAPHS * HC) sums[i] = 0.f;
}

// ---------------- GEMM body (device): MFMA + fused attention scores ----------------
// Out: fp16 sub-table layout. WT staged in LDS with k ^= (n&7)<<3 swizzle.
// Wave: 8 col-tiles x 4 K-steps of mfma_f32_16x16x32_f16.
// C/D: col=lane&15, row=(lane>>4)*4+reg (m89).
template<bool FP32IN>
__device__ __forceinline__ void gemm_body(int bid, int t, _Float16 (*wt)[128],
                                          const void* __restrict__ Xin,
                                          const _Float16* __restrict__ WT,
                                          const float* __restrict__ att_s,
                                          const float* __restrict__ att_d,
                                          _Float16* __restrict__ H16,
                                          float2* __restrict__ a_src,
                                          float2* __restrict__ a_dst) {
    for (int i = t; i < 128 * 16; i += 256) {
        int n = i >> 4, ch = i & 15;
        int k0 = ch * 8;
        half8 v = *(const half8*)&WT[n * 128 + k0];
        *(half8*)&wt[n][k0 ^ ((n & 7) << 3)] = v;
    }

    int w = t >> 6, lane = t & 63;
    int hi = lane >> 4, l16 = lane & 15;
    int rbase = bid * 64 + w * 16;
    int arow = min(rbase + l16, N_NODES - 1);

    half8 a[4];
    if (FP32IN) {
        const float* X = (const float*)Xin;
#pragma unroll
        for (int kb = 0; kb < 4; ++kb) {
            int k0 = kb * 32 + hi * 8;
            float4 x0 = *(const float4*)&X[(size_t)arow * 128 + k0];
            float4 x1 = *(const float4*)&X[(size_t)arow * 128 + k0 + 4];
            half8 v;
            v[0] = (_Float16)x0.x; v[1] = (_Float16)x0.y;
            v[2] = (_Float16)x0.z; v[3] = (_Float16)x0.w;
            v[4] = (_Float16)x1.x; v[5] = (_Float16)x1.y;
            v[6] = (_Float16)x1.z; v[7] = (_Float16)x1.w;
            a[kb] = v;
        }
    } else {
        // sub-table layout: slice kb, row arow, cols hi*8..+8
        const _Float16* X = (const _Float16*)Xin;
#pragma unroll
        for (int kb = 0; kb < 4; ++kb)
            a[kb] = *(const half8*)&X[((size_t)kb * N_NODES + arow) * 32 + hi * 8];
    }

    __syncthreads();

    float4v acc[8];
#pragma unroll
    for (int ct = 0; ct < 8; ++ct) {
        float4v c = {0.f, 0.f, 0.f, 0.f};
        int n = ct * 16 + l16;               // B: lane&15 = col
#pragma unroll
        for (int kb = 0; kb < 4; ++kb) {
            int k0 = (kb * 32 + hi * 8) ^ ((n & 7) << 3);
            half8 b = *(const half8*)&wt[n][k0];
            c = __builtin_amdgcn_mfma_f32_16x16x32_f16(a[kb], b, c, 0, 0, 0);
        }
        acc[ct] = c;
    }

    int grow0 = rbase + hi * 4;
#pragma unroll
    for (int ct = 0; ct < 8; ++ct) {
        int sl = ct >> 1;                    // feature slice
        int cc = (ct & 1) * 16 + l16;        // col within slice
#pragma unroll
        for (int r = 0; r < 4; ++r) {
            int grow = grow0 + r;
            if (grow < N_NODES)
                H16[((size_t)sl * N_NODES + grow) * 32 + cc] = (_Float16)acc[ct][r];
        }
    }

    float as_[8], ad_[8];
#pragma unroll
    for (int ct = 0; ct < 8; ++ct) {
        as_[ct] = att_s[ct * 16 + l16];
        ad_[ct] = att_d[ct * 16 + l16];
    }
#pragma unroll
    for (int r = 0; r < 4; ++r) {
        float s0 = 0.f, s1 = 0.f, d0 = 0.f, d1 = 0.f;
#pragma unroll
        for (int ct = 0; ct < 4; ++ct) { s0 += acc[ct][r] * as_[ct]; d0 += acc[ct][r] * ad_[ct]; }
#pragma unroll
        for (int ct = 4; ct < 8; ++ct) { s1 += acc[ct][r] * as_[ct]; d1 += acc[ct][r] * ad_[ct]; }
        for (int off = 1; off < 16; off <<= 1) {
            s0 += __shfl_xor(s0, off); s1 += __shfl_xor(s1, off);
            d0 += __shfl_xor(d0, off); d1 += __shfl_xor(d1, off);
        }
        int grow = grow0 + r;
        if (l16 == 0 && grow < N_NODES) {
            a_src[grow] = make_float2(s0, s1);
            a_dst[grow] = make_float2(d0, d1);
        }
    }
}

// ---------------- bucketA body (device): bin edges by dst bucket ----------------
__device__ __forceinline__ void bucketA_body(int bid, int t,
                                             int* hist, int* lbase,
                                             const int* __restrict__ ei,
                                             int* __restrict__ tails,
                                             int* __restrict__ bdata) {
    int e0 = bid * (256 * EPT);
    for (int i = t; i < NBUCK; i += 256) hist[i] = 0;
    __syncthreads();

    int bb[EPT], pk[EPT], rk[EPT];
#pragma unroll
    for (int i = 0; i < EPT; ++i) {
        int e = e0 + i * 256 + t;
        bb[i] = -1;
        if (e < ETOT) {
            int s, d;
            if (e < N_EDGES) { s = ei[e]; d = ei[N_EDGES + e]; }
            else             { s = d = e - N_EDGES; }
            bb[i] = d >> 8;
            pk[i] = s | ((d & 255) << 16);
            rk[i] = atomicAdd(&hist[bb[i]], 1);
        }
    }
    __syncthreads();
    for (int i = t; i < NBUCK; i += 256)
        lbase[i] = atomicAdd(&tails[i], hist[i]);
    __syncthreads();
#pragma unroll
    for (int i = 0; i < EPT; ++i)
        if (bb[i] >= 0) bdata[bb[i] * BCAP + lbase[bb[i]] + rk[i]] = pk[i];
}

// ---------------- fused: gemm layer-1 blocks + bucketA blocks ----------------
__global__ __launch_bounds__(256) void fusedA(const float* __restrict__ x,
                                              const _Float16* __restrict__ WT1,
                                              const float* __restrict__ att_s,
                                              const float* __restrict__ att_d,
                                              _Float16* __restrict__ H16,
                                              float2* __restrict__ a_src,
                                              float2* __restrict__ a_dst,
                                              const int* __restrict__ ei,
                                              int* __restrict__ tails,
                                              int* __restrict__ bdata) {
    __shared__ _Float16 wt[128][128];   // 32 KB (gemm blocks)
    __shared__ int hist[NBUCK];         // bucketA blocks
    __shared__ int lbase[NBUCK];
    int t = threadIdx.x;
    if (blockIdx.x < GEMMB) {
        gemm_body<true>(blockIdx.x, t, wt, x, WT1, att_s, att_d, H16, a_src, a_dst);
    } else {
        bucketA_body(blockIdx.x - GEMMB, t, hist, lbase, ei, tails, bdata);
    }
}

// ---------------- standalone gemm (layer 2) ----------------
__global__ __launch_bounds__(256) void gemmMFMA(const _Float16* __restrict__ Xin,
                                                const _Float16* __restrict__ WT,
                                                const float* __restrict__ att_s,
                                                const float* __restrict__ att_d,
                                                _Float16* __restrict__ H16,
                                                float2* __restrict__ a_src,
                                                float2* __restrict__ a_dst) {
    __shared__ _Float16 wt[128][128];
    gemm_body<false>(blockIdx.x, threadIdx.x, wt, Xin, WT, att_s, att_d, H16, a_src, a_dst);
}

// ---------------- bucketB: per-bucket CSR fill (self-computed base) ----------------
__global__ __launch_bounds__(256) void bucketB(const int* __restrict__ bdata,
                                               const int* __restrict__ tails,
                                               int* __restrict__ rowptr,
                                               int* __restrict__ csr) {
    __shared__ int hist[256];
    __shared__ int scanws[256];
    int b = blockIdx.x;
    int t = threadIdx.x;

    int cb = (t < NBUCK) ? tails[t] : 0;
    scanws[t] = cb;
    __syncthreads();
    for (int off = 1; off < 256; off <<= 1) {
        int add = (t >= off) ? scanws[t - off] : 0;
        __syncthreads();
        scanws[t] += add;
        __syncthreads();
    }
    int base = scanws[b] - tails[b];       // exclusive prefix at b (uniform read)
    if (b == NBUCK - 1 && t == 0) rowptr[N_NODES] = scanws[NBUCK - 1];
    int cnt = tails[b];
    int nodes0 = b << 8;
    int nnodes = min(256, N_NODES - nodes0);
    const int* bd = &bdata[b * BCAP];
    __syncthreads();

    hist[t] = 0;
    __syncthreads();
    for (int j = t; j < cnt; j += 256) atomicAdd(&hist[bd[j] >> 16], 1);
    __syncthreads();
    scanws[t] = hist[t];
    __syncthreads();
    for (int off = 1; off < 256; off <<= 1) {
        int add = (t >= off) ? scanws[t - off] : 0;
        __syncthreads();
        scanws[t] += add;
        __syncthreads();
    }
    int excl = scanws[t] - hist[t];
    if (t < nnodes) rowptr[nodes0 + t] = base + excl;
    __syncthreads();
    hist[t] = excl;
    __syncthreads();
    for (int j = t; j < cnt; j += 256) {
        int pkv = bd[j];
        int pos = atomicAdd(&hist[pkv >> 16], 1);
        csr[base + pos] = pkv & 0xFFFF;
    }
}

__device__ __forceinline__ float leaky(float x) { return x > 0.f ? x : NEG * x; }

// ---------------- softmax + aggregation: feature-sliced ----------------
// Block = 4 waves = 4 nodes, ONE feature slice (slice = bid & 3). With
// round-robin block->XCD dispatch, each XCD touches one 3.2 MB slice ->
// L2-resident gathers (T1 mechanism). Wave: 16 groups x 4 lanes; group g
// walks every 16th edge; lane owns 8 features (16 B load; group covers the
// 64 B slice row). csr read nontemporal (streaming, avoid L2 pollution).
// POOL=false: write fp16 slice output. POOL=true: LDS-staged pool flush with
// per-block graph dedupe (1 atomic per feature per distinct graph per block —
// do NOT replace with per-wave atomics: sorted batch => all resident waves
// share a graph and serialize on the same addresses; measured 10x blowup).
template<bool POOL>
__global__ __launch_bounds__(256) void aggk(const _Float16* __restrict__ H16,
                                            const float2* __restrict__ a_src,
                                            const float2* __restrict__ a_dst,
                                            const int* __restrict__ rowptr,
                                            const int* __restrict__ csr,
                                            const float* __restrict__ bias,
                                            _Float16* __restrict__ out16,
                                            const int* __restrict__ batch,
                                            float* __restrict__ sums) {
    __shared__ float pbuf[POOL ? 4 : 1][32];
    __shared__ int pg[4];
    int t = threadIdx.x;
    int bid = blockIdx.x;
    int slice = bid & 3;                      // consistent per XCD (bid%8 -> XCD)
    int w = t >> 6;
    int wid = (bid >> 2) * 4 + w;             // node; grid covers N_NODES exactly
    int lane = t & 63;
    int rbeg = rowptr[wid], rend = rowptr[wid + 1];
    float2 ad = a_dst[wid];

    int grp = lane >> 2;        // 0..15
    int gl  = lane & 3;         // lane within group: features gl*8..+7 of slice
    int head = slice >> 1;      // slices 0,1 = head0; 2,3 = head1 (wave-uniform)
    float adh = head ? ad.y : ad.x;
    int f = gl * 8;

    const _Float16* Hs = &H16[(size_t)slice * N_NODES * 32];

    float acc[8] = {0.f, 0.f, 0.f, 0.f, 0.f, 0.f, 0.f, 0.f};
    float denom = 0.f;
    for (int j = rbeg + grp; j < rend; j += 16) {
        int s = __builtin_nontemporal_load(&csr[j]);
        float2 as = a_src[s];
        float wgt = __expf(leaky((head ? as.y : as.x) + adh));
        uint4 raw = *(const uint4*)&Hs[(size_t)s * 32 + f];
        float2 p;
        p = __half22float2(*(__half2*)&raw.x); acc[0] += wgt * p.x; acc[1] += wgt * p.y;
        p = __half22float2(*(__half2*)&raw.y); acc[2] += wgt * p.x; acc[3] += wgt * p.y;
        p = __half22float2(*(__half2*)&raw.z); acc[4] += wgt * p.x; acc[5] += wgt * p.y;
        p = __half22float2(*(__half2*)&raw.w); acc[6] += wgt * p.x; acc[7] += wgt * p.y;
        denom += wgt;
    }
    // reduce across the 16 groups (lane bits 2..5)
#pragma unroll
    for (int off = 4; off <= 32; off <<= 1) {
#pragma unroll
        for (int i = 0; i < 8; ++i) acc[i] += __shfl_xor(acc[i], off);
        denom += __shfl_xor(denom, off);
    }

    float inv = 1.f / (denom + 1e-16f);
    if (POOL) {
        if (grp == 0) {
            if (gl == 0) pg[w] = batch[wid];
#pragma unroll
            for (int i = 0; i < 8; ++i)
                pbuf[w][f + i] = fmaxf(acc[i] * inv + bias[slice * 32 + f + i], 0.f);
        }
        __syncthreads();
        // flush: dedupe the 4 wave-slots by graph id, 1 atomic per feat per graph
        if (t < 32) {
#pragma unroll
            for (int ws = 0; ws < 4; ++ws) {
                bool leader = true;
#pragma unroll
                for (int v = 0; v < ws; ++v) leader = leader && (pg[ws] != pg[v]);
                if (leader) {
                    float s = pbuf[ws][t];
#pragma unroll
                    for (int u = ws + 1; u < 4; ++u)
                        if (pg[u] == pg[ws]) s += pbuf[u][t];
                    atomicAdd(&sums[pg[ws] * 128 + slice * 32 + t], s);
                }
            }
        }
    } else {
        if (grp == 0) {
            half8 h;
#pragma unroll
            for (int i = 0; i < 8; ++i)
                h[i] = (_Float16)fmaxf(acc[i] * inv + bias[slice * 32 + f + i], 0.f);
            *(half8*)&out16[((size_t)slice * N_NODES + wid) * 32 + f] = h;
        }
    }
}

// ---------------- final linear (counts via binary search, sorted batch) ----------------
__global__ void finalk(const float* __restrict__ sums, const int* __restrict__ batch,
                       const float* __restrict__ Wl, const float* __restrict__ bl,
                       float* __restrict__ out) {
    int t = threadIdx.x;
    if (t >= GRAPHS * OUTF) return;
    int g = t / OUTF, o = t % OUTF;
    int lo = 0, hi = N_NODES;
    while (lo < hi) { int m = (lo + hi) >> 1; if (batch[m] < g) lo = m + 1; else hi = m; }
    int lb = lo;
    lo = 0; hi = N_NODES;
    while (lo < hi) { int m = (lo + hi) >> 1; if (batch[m] < g + 1) lo = m + 1; else hi = m; }
    float inv = 1.f / fmaxf((float)(lo - lb), 1.f);
    float acc = 0.f;
#pragma unroll 8
    for (int k = 0; k < 128; ++k) acc += sums[g * 128 + k] * Wl[k * OUTF + o];
    out[t] = acc * inv + bl[o];
}

extern "C" void kernel_launch(void* const* d_in, const int* in_sizes, int n_in,
                              void* d_out, int out_size, void* d_ws, size_t ws_size,
                              hipStream_t stream) {
    const float* x        = (const float*)d_in[0];
    const int*   ei       = (const int*)d_in[1];
    const int*   batch    = (const int*)d_in[2];
    const float* W1       = (const float*)d_in[3];
    const float* att_src1 = (const float*)d_in[4];
    const float* att_dst1 = (const float*)d_in[5];
    const float* b1       = (const float*)d_in[6];
    const float* W2       = (const float*)d_in[7];
    const float* att_src2 = (const float*)d_in[8];
    const float* att_dst2 = (const float*)d_in[9];
    const float* b2       = (const float*)d_in[10];
    const float* Wl       = (const float*)d_in[11];
    const float* bl       = (const float*)d_in[12];
    float* out = (float*)d_out;

    size_t off = 0;
    auto alloc = [&](size_t bytes) -> void* {
        void* p = (char*)d_ws + off;
        off = (off + bytes + 255) & ~(size_t)255;
        return p;
    };
    _Float16* H16     = (_Float16*)alloc((size_t)N_NODES * 128 * 2);
    _Float16* B16     = (_Float16*)alloc((size_t)N_NODES * 128 * 2);
    _Float16* WT1     = (_Float16*)alloc(16384 * 2);
    _Float16* WT2     = (_Float16*)alloc(16384 * 2);
    float2*   a_src   = (float2*)alloc((size_t)N_NODES * 8);
    float2*   a_dst   = (float2*)alloc((size_t)N_NODES * 8);
    int*      bdata   = (int*)alloc((size_t)NBUCK * BCAP * 4);
    int*      tails   = (int*)alloc(NBUCK * 4);
    int*      rowptr  = (int*)alloc((size_t)(N_NODES + 1) * 4);
    int*      csr     = (int*)alloc((size_t)ETOT * 4);
    float*    sums    = (float*)alloc((size_t)GRAPHS * HC * 4);

    const int aggBlocks = N_NODES;            // 4 nodes x 4 slices per... 50000 blocks

    // 1. setup (weights fp16-transpose, zero tails/sums)
    setupk<<<64, 256, 0, stream>>>(W1, W2, WT1, WT2, tails, sums);
    // 2. layer-1 GEMM + bucketA in one dispatch (independent work)
    fusedA<<<GEMMB + ABLK, 256, 0, stream>>>(x, WT1, att_src1, att_dst1,
                                             H16, a_src, a_dst, ei, tails, bdata);
    // 3. per-bucket CSR fill (self-computes base from tails)
    bucketB<<<NBUCK, 256, 0, stream>>>(bdata, tails, rowptr, csr);
    // 4. layer-1 aggregation (feature-sliced, writes fp16 sub-tables)
    aggk<false><<<aggBlocks, 256, 0, stream>>>(H16, a_src, a_dst,
                                               rowptr, csr, b1, B16, batch, sums);
    // 5. layer-2 GEMM (reads sub-table layout)
    gemmMFMA<<<GEMMB, 256, 0, stream>>>(B16, WT2, att_src2, att_dst2,
                                        H16, a_src, a_dst);
    // 6. layer-2 aggregation + fused global-mean-pool (LDS flush)
    aggk<true><<<aggBlocks, 256, 0, stream>>>(H16, a_src, a_dst,
                                              rowptr, csr, b2, nullptr, batch, sums);
    // 7. final linear (+ per-graph counts via binary search)
    finalk<<<1, 640, 0, stream>>>(sums, batch, Wl, bl, out);
}

// Round 16
// 160.392 us; speedup vs baseline: 1.7542x; 1.7542x over previous
//
#include <hip/hip_runtime.h>
#include <hip/hip_fp16.h>
#include <math.h>

#define N_NODES 50000
#define N_EDGES 800000
#define ETOT    850000   // N_EDGES + N_NODES self-loops
#define GRAPHS  64
#define FIN     128
#define HC      128      // HEADS*HID
#define OUTF    10
#define NEG     0.2f

#define NBUCK   196      // ceil(50000/256) buckets of 256 dst nodes
#define BCAP    8192     // slots per bucket (mean 4338, sigma ~66 -> safe)
#define EPT     8        // edges per thread in bucketA
#define GEMMB   782      // (N_NODES+63)/64
#define ABLK    416      // (ETOT+2047)/2048

using half8   = __attribute__((ext_vector_type(8))) _Float16;
using float4v = __attribute__((ext_vector_type(4))) float;

// ---------------- setup: W->fp16 transposed, zero tails + pool sums ----------------
__global__ void setupk(const float* __restrict__ W1, const float* __restrict__ W2,
                       _Float16* __restrict__ WT1, _Float16* __restrict__ WT2,
                       int* __restrict__ tails, float* __restrict__ sums) {
    int i = blockIdx.x * 256 + threadIdx.x;
    if (i < 16384) {
        int n = i >> 7, k = i & 127;          // output index WT[n][k]
        WT1[i] = (_Float16)W1[k * 128 + n];
        WT2[i] = (_Float16)W2[k * 128 + n];
    }
    if (i < NBUCK) tails[i] = 0;
    if (i < GRAPHS * HC) sums[i] = 0.f;
}

// ---------------- GEMM body (device): MFMA + fused attention scores ----------------
// H16[M,128] = fp16( Xin[M,128] @ W[128,128] ), scores from fp32 acc.
// WT staged in LDS with k ^= (n&7)<<3 swizzle. Wave: 8 col-tiles x 4 K-steps
// of mfma_f32_16x16x32_f16. C/D: col=lane&15, row=(lane>>4)*4+reg (m89).
template<bool FP32IN>
__device__ __forceinline__ void gemm_body(int bid, int t, _Float16 (*wt)[128],
                                          const void* __restrict__ Xin,
                                          const _Float16* __restrict__ WT,
                                          const float* __restrict__ att_s,
                                          const float* __restrict__ att_d,
                                          _Float16* __restrict__ H16,
                                          float2* __restrict__ a_src,
                                          float2* __restrict__ a_dst) {
    for (int i = t; i < 128 * 16; i += 256) {
        int n = i >> 4, ch = i & 15;
        int k0 = ch * 8;
        half8 v = *(const half8*)&WT[n * 128 + k0];
        *(half8*)&wt[n][k0 ^ ((n & 7) << 3)] = v;
    }

    int w = t >> 6, lane = t & 63;
    int hi = lane >> 4, l16 = lane & 15;
    int rbase = bid * 64 + w * 16;
    int arow = min(rbase + l16, N_NODES - 1);

    half8 a[4];
    if (FP32IN) {
        const float* X = (const float*)Xin;
#pragma unroll
        for (int kb = 0; kb < 4; ++kb) {
            int k0 = kb * 32 + hi * 8;
            float4 x0 = *(const float4*)&X[(size_t)arow * 128 + k0];
            float4 x1 = *(const float4*)&X[(size_t)arow * 128 + k0 + 4];
            half8 v;
            v[0] = (_Float16)x0.x; v[1] = (_Float16)x0.y;
            v[2] = (_Float16)x0.z; v[3] = (_Float16)x0.w;
            v[4] = (_Float16)x1.x; v[5] = (_Float16)x1.y;
            v[6] = (_Float16)x1.z; v[7] = (_Float16)x1.w;
            a[kb] = v;
        }
    } else {
        const _Float16* X = (const _Float16*)Xin;
#pragma unroll
        for (int kb = 0; kb < 4; ++kb)
            a[kb] = *(const half8*)&X[(size_t)arow * 128 + kb * 32 + hi * 8];
    }

    __syncthreads();

    float4v acc[8];
#pragma unroll
    for (int ct = 0; ct < 8; ++ct) {
        float4v c = {0.f, 0.f, 0.f, 0.f};
        int n = ct * 16 + l16;               // B: lane&15 = col
#pragma unroll
        for (int kb = 0; kb < 4; ++kb) {
            int k0 = (kb * 32 + hi * 8) ^ ((n & 7) << 3);
            half8 b = *(const half8*)&wt[n][k0];
            c = __builtin_amdgcn_mfma_f32_16x16x32_f16(a[kb], b, c, 0, 0, 0);
        }
        acc[ct] = c;
    }

    int grow0 = rbase + hi * 4;
#pragma unroll
    for (int ct = 0; ct < 8; ++ct) {
#pragma unroll
        for (int r = 0; r < 4; ++r) {
            int grow = grow0 + r;
            if (grow < N_NODES)
                H16[(size_t)grow * 128 + ct * 16 + l16] = (_Float16)acc[ct][r];
        }
    }

    float as_[8], ad_[8];
#pragma unroll
    for (int ct = 0; ct < 8; ++ct) {
        as_[ct] = att_s[ct * 16 + l16];
        ad_[ct] = att_d[ct * 16 + l16];
    }
#pragma unroll
    for (int r = 0; r < 4; ++r) {
        float s0 = 0.f, s1 = 0.f, d0 = 0.f, d1 = 0.f;
#pragma unroll
        for (int ct = 0; ct < 4; ++ct) { s0 += acc[ct][r] * as_[ct]; d0 += acc[ct][r] * ad_[ct]; }
#pragma unroll
        for (int ct = 4; ct < 8; ++ct) { s1 += acc[ct][r] * as_[ct]; d1 += acc[ct][r] * ad_[ct]; }
        for (int off = 1; off < 16; off <<= 1) {
            s0 += __shfl_xor(s0, off); s1 += __shfl_xor(s1, off);
            d0 += __shfl_xor(d0, off); d1 += __shfl_xor(d1, off);
        }
        int grow = grow0 + r;
        if (l16 == 0 && grow < N_NODES) {
            a_src[grow] = make_float2(s0, s1);
            a_dst[grow] = make_float2(d0, d1);
        }
    }
}

// ---------------- bucketA body (device): bin edges by dst bucket ----------------
__device__ __forceinline__ void bucketA_body(int bid, int t,
                                             int* hist, int* lbase,
                                             const int* __restrict__ ei,
                                             int* __restrict__ tails,
                                             int* __restrict__ bdata) {
    int e0 = bid * (256 * EPT);
    for (int i = t; i < NBUCK; i += 256) hist[i] = 0;
    __syncthreads();

    int bb[EPT], pk[EPT], rk[EPT];
#pragma unroll
    for (int i = 0; i < EPT; ++i) {
        int e = e0 + i * 256 + t;
        bb[i] = -1;
        if (e < ETOT) {
            int s, d;
            if (e < N_EDGES) { s = ei[e]; d = ei[N_EDGES + e]; }
            else             { s = d = e - N_EDGES; }
            bb[i] = d >> 8;
            pk[i] = s | ((d & 255) << 16);
            rk[i] = atomicAdd(&hist[bb[i]], 1);
        }
    }
    __syncthreads();
    for (int i = t; i < NBUCK; i += 256)
        lbase[i] = atomicAdd(&tails[i], hist[i]);
    __syncthreads();
#pragma unroll
    for (int i = 0; i < EPT; ++i)
        if (bb[i] >= 0) bdata[bb[i] * BCAP + lbase[bb[i]] + rk[i]] = pk[i];
}

// ---------------- fused: gemm layer-1 blocks + bucketA blocks ----------------
__global__ __launch_bounds__(256) void fusedA(const float* __restrict__ x,
                                              const _Float16* __restrict__ WT1,
                                              const float* __restrict__ att_s,
                                              const float* __restrict__ att_d,
                                              _Float16* __restrict__ H16,
                                              float2* __restrict__ a_src,
                                              float2* __restrict__ a_dst,
                                              const int* __restrict__ ei,
                                              int* __restrict__ tails,
                                              int* __restrict__ bdata) {
    __shared__ _Float16 wt[128][128];   // 32 KB (gemm blocks)
    __shared__ int hist[NBUCK];         // bucketA blocks
    __shared__ int lbase[NBUCK];
    int t = threadIdx.x;
    if (blockIdx.x < GEMMB) {
        gemm_body<true>(blockIdx.x, t, wt, x, WT1, att_s, att_d, H16, a_src, a_dst);
    } else {
        bucketA_body(blockIdx.x - GEMMB, t, hist, lbase, ei, tails, bdata);
    }
}

// ---------------- standalone gemm (layer 2) ----------------
__global__ __launch_bounds__(256) void gemmMFMA(const _Float16* __restrict__ Xin,
                                                const _Float16* __restrict__ WT,
                                                const float* __restrict__ att_s,
                                                const float* __restrict__ att_d,
                                                _Float16* __restrict__ H16,
                                                float2* __restrict__ a_src,
                                                float2* __restrict__ a_dst) {
    __shared__ _Float16 wt[128][128];
    gemm_body<false>(blockIdx.x, threadIdx.x, wt, Xin, WT, att_s, att_d, H16, a_src, a_dst);
}

// ---------------- bucketB: per-bucket CSR fill (self-computed base) ----------------
__global__ __launch_bounds__(256) void bucketB(const int* __restrict__ bdata,
                                               const int* __restrict__ tails,
                                               int* __restrict__ rowptr,
                                               int* __restrict__ csr) {
    __shared__ int hist[256];
    __shared__ int scanws[256];
    int b = blockIdx.x;
    int t = threadIdx.x;

    // scan bucket counts -> this bucket's csr base (replaces scanBuckets kernel)
    int cb = (t < NBUCK) ? tails[t] : 0;
    scanws[t] = cb;
    __syncthreads();
    for (int off = 1; off < 256; off <<= 1) {
        int add = (t >= off) ? scanws[t - off] : 0;
        __syncthreads();
        scanws[t] += add;
        __syncthreads();
    }
    int base = scanws[b] - tails[b];       // exclusive prefix at b (uniform read)
    if (b == NBUCK - 1 && t == 0) rowptr[N_NODES] = scanws[NBUCK - 1];
    int cnt = tails[b];
    int nodes0 = b << 8;
    int nnodes = min(256, N_NODES - nodes0);
    const int* bd = &bdata[b * BCAP];
    __syncthreads();

    hist[t] = 0;
    __syncthreads();
    for (int j = t; j < cnt; j += 256) atomicAdd(&hist[bd[j] >> 16], 1);
    __syncthreads();
    scanws[t] = hist[t];
    __syncthreads();
    for (int off = 1; off < 256; off <<= 1) {
        int add = (t >= off) ? scanws[t - off] : 0;
        __syncthreads();
        scanws[t] += add;
        __syncthreads();
    }
    int excl = scanws[t] - hist[t];
    if (t < nnodes) rowptr[nodes0 + t] = base + excl;
    __syncthreads();
    hist[t] = excl;
    __syncthreads();
    for (int j = t; j < cnt; j += 256) {
        int pkv = bd[j];
        int pos = atomicAdd(&hist[pkv >> 16], 1);
        csr[base + pos] = pkv & 0xFFFF;
    }
}

__device__ __forceinline__ float leaky(float x) { return x > 0.f ? x : NEG * x; }

// ---------------- softmax + aggregation: one wave per dst node ----------------
// R11/R13-verified optimum: 4 groups of 16 lanes, group g walks every 4th
// edge; lane owns 8 features (one uint4 = 16B load; group covers the 256B
// row), inline a_src read, unroll 2. Reduce via shfl_xor 16,32.
// Families tried and measured WORSE: 8x8 groups (+15us), depth-2 pipeline
// (+5us), XCD feature-slicing (+67us). Do not revisit without new evidence.
// POOL=false: write fp16 node output. POOL=true: LDS-staged pool flush with
// per-block graph dedupe (1 atomic per feature per distinct graph per block —
// do NOT replace with per-wave atomics: sorted batch => all resident waves
// share a graph and serialize on the same 128 addresses; measured 10x blowup).
template<bool POOL>
__global__ __launch_bounds__(256) void aggk(const __half* __restrict__ H16,
                                            const float2* __restrict__ a_src,
                                            const float2* __restrict__ a_dst,
                                            const int* __restrict__ rowptr,
                                            const int* __restrict__ csr,
                                            const float* __restrict__ bias,
                                            _Float16* __restrict__ out16,
                                            const int* __restrict__ batch,
                                            float* __restrict__ sums) {
    __shared__ float pbuf[POOL ? 4 : 1][128];
    __shared__ int pg[4];
    int t = threadIdx.x;
    int wid = (blockIdx.x * 256 + t) >> 6;    // grid covers exactly N_NODES
    int w = t >> 6;
    int lane = t & 63;
    int rbeg = rowptr[wid], rend = rowptr[wid + 1];
    float2 ad = a_dst[wid];

    int grp = lane >> 4;        // 0..3
    int gl  = lane & 15;        // lane within group: features gl*8..+7
    int head = gl >> 3;         // gl<8 -> head0 (f<64), else head1
    float adh = head ? ad.y : ad.x;
    int f = gl * 8;

    float acc[8] = {0.f, 0.f, 0.f, 0.f, 0.f, 0.f, 0.f, 0.f};
    float denom = 0.f;
#pragma unroll 2
    for (int j = rbeg + grp; j < rend; j += 4) {
        int s = csr[j];
        float2 as = a_src[s];
        float wgt = __expf(leaky((head ? as.y : as.x) + adh));
        uint4 raw = *(const uint4*)&H16[(size_t)s * 128 + f];
        float2 p;
        p = __half22float2(*(__half2*)&raw.x); acc[0] += wgt * p.x; acc[1] += wgt * p.y;
        p = __half22float2(*(__half2*)&raw.y); acc[2] += wgt * p.x; acc[3] += wgt * p.y;
        p = __half22float2(*(__half2*)&raw.z); acc[4] += wgt * p.x; acc[5] += wgt * p.y;
        p = __half22float2(*(__half2*)&raw.w); acc[6] += wgt * p.x; acc[7] += wgt * p.y;
        denom += wgt;
    }
    // reduce across the 4 groups (lane bits 4,5)
#pragma unroll
    for (int off = 16; off <= 32; off <<= 1) {
#pragma unroll
        for (int i = 0; i < 8; ++i) acc[i] += __shfl_xor(acc[i], off);
        denom += __shfl_xor(denom, off);
    }

    float inv = 1.f / (denom + 1e-16f);
    if (POOL) {
        if (grp == 0) {
            if (gl == 0) pg[w] = batch[wid];
#pragma unroll
            for (int i = 0; i < 8; ++i)
                pbuf[w][f + i] = fmaxf(acc[i] * inv + bias[f + i], 0.f);
        }
        __syncthreads();
        // flush: dedupe the 4 wave-slots by graph id, 1 atomic per feat per graph
        if (t < 128) {
#pragma unroll
            for (int ws = 0; ws < 4; ++ws) {
                bool leader = true;
#pragma unroll
                for (int v = 0; v < ws; ++v) leader = leader && (pg[ws] != pg[v]);
                if (leader) {
                    float s = pbuf[ws][t];
#pragma unroll
                    for (int u = ws + 1; u < 4; ++u)
                        if (pg[u] == pg[ws]) s += pbuf[u][t];
                    atomicAdd(&sums[pg[ws] * 128 + t], s);
                }
            }
        }
    } else {
        if (grp == 0) {
            half8 h;
#pragma unroll
            for (int i = 0; i < 8; ++i)
                h[i] = (_Float16)fmaxf(acc[i] * inv + bias[f + i], 0.f);
            *(half8*)&out16[(size_t)wid * 128 + f] = h;
        }
    }
}

// ---------------- final linear (counts via binary search, sorted batch) ----------------
__global__ void finalk(const float* __restrict__ sums, const int* __restrict__ batch,
                       const float* __restrict__ Wl, const float* __restrict__ bl,
                       float* __restrict__ out) {
    int t = threadIdx.x;
    if (t >= GRAPHS * OUTF) return;
    int g = t / OUTF, o = t % OUTF;
    int lo = 0, hi = N_NODES;
    while (lo < hi) { int m = (lo + hi) >> 1; if (batch[m] < g) lo = m + 1; else hi = m; }
    int lb = lo;
    lo = 0; hi = N_NODES;
    while (lo < hi) { int m = (lo + hi) >> 1; if (batch[m] < g + 1) lo = m + 1; else hi = m; }
    float inv = 1.f / fmaxf((float)(lo - lb), 1.f);
    float acc = 0.f;
#pragma unroll 8
    for (int k = 0; k < 128; ++k) acc += sums[g * 128 + k] * Wl[k * OUTF + o];
    out[t] = acc * inv + bl[o];
}

extern "C" void kernel_launch(void* const* d_in, const int* in_sizes, int n_in,
                              void* d_out, int out_size, void* d_ws, size_t ws_size,
                              hipStream_t stream) {
    const float* x        = (const float*)d_in[0];
    const int*   ei       = (const int*)d_in[1];
    const int*   batch    = (const int*)d_in[2];
    const float* W1       = (const float*)d_in[3];
    const float* att_src1 = (const float*)d_in[4];
    const float* att_dst1 = (const float*)d_in[5];
    const float* b1       = (const float*)d_in[6];
    const float* W2       = (const float*)d_in[7];
    const float* att_src2 = (const float*)d_in[8];
    const float* att_dst2 = (const float*)d_in[9];
    const float* b2       = (const float*)d_in[10];
    const float* Wl       = (const float*)d_in[11];
    const float* bl       = (const float*)d_in[12];
    float* out = (float*)d_out;

    size_t off = 0;
    auto alloc = [&](size_t bytes) -> void* {
        void* p = (char*)d_ws + off;
        off = (off + bytes + 255) & ~(size_t)255;
        return p;
    };
    _Float16* H16     = (_Float16*)alloc((size_t)N_NODES * 128 * 2);
    _Float16* B16     = (_Float16*)alloc((size_t)N_NODES * 128 * 2);
    _Float16* WT1     = (_Float16*)alloc(16384 * 2);
    _Float16* WT2     = (_Float16*)alloc(16384 * 2);
    float2*   a_src   = (float2*)alloc((size_t)N_NODES * 8);
    float2*   a_dst   = (float2*)alloc((size_t)N_NODES * 8);
    int*      bdata   = (int*)alloc((size_t)NBUCK * BCAP * 4);
    int*      tails   = (int*)alloc(NBUCK * 4);
    int*      rowptr  = (int*)alloc((size_t)(N_NODES + 1) * 4);
    int*      csr     = (int*)alloc((size_t)ETOT * 4);
    float*    sums    = (float*)alloc((size_t)GRAPHS * HC * 4);

    const int waveBlocks = (N_NODES * 64 + 255) / 256;      // 12500 (exact)

    // 1. setup (weights fp16-transpose, zero tails/sums)
    setupk<<<64, 256, 0, stream>>>(W1, W2, WT1, WT2, tails, sums);
    // 2. layer-1 GEMM + bucketA in one dispatch (independent work)
    fusedA<<<GEMMB + ABLK, 256, 0, stream>>>(x, WT1, att_src1, att_dst1,
                                             H16, a_src, a_dst, ei, tails, bdata);
    // 3. per-bucket CSR fill (self-computes base from tails)
    bucketB<<<NBUCK, 256, 0, stream>>>(bdata, tails, rowptr, csr);
    // 4. layer-1 aggregation (writes fp16 node features)
    aggk<false><<<waveBlocks, 256, 0, stream>>>((const __half*)H16, a_src, a_dst,
                                                rowptr, csr, b1, B16, batch, sums);
    // 5. layer-2 GEMM
    gemmMFMA<<<GEMMB, 256, 0, stream>>>(B16, WT2, att_src2, att_dst2,
                                        H16, a_src, a_dst);
    // 6. layer-2 aggregation + fused global-mean-pool (LDS flush)
    aggk<true><<<waveBlocks, 256, 0, stream>>>((const __half*)H16, a_src, a_dst,
                                               rowptr, csr, b2, nullptr, batch, sums);
    // 7. final linear (+ per-graph counts via binary search)
    finalk<<<1, 640, 0, stream>>>(sums, batch, Wl, bl, out);
}